// Round 8
// baseline (729.782 us; speedup 1.0000x reference)
//
#include <hip/hip_runtime.h>

#define D_DIM 256
#define N_TOK 32768
#define K_CB  8192
#define TAU   0.03f

typedef float  f32x16 __attribute__((ext_vector_type(16)));
typedef float  f32x4  __attribute__((ext_vector_type(4)));
typedef short  s16x8  __attribute__((ext_vector_type(8)));

// ---- workspace layout (bytes) ----
#define OFF_ESQ   0                        // 8192 f32 (32 KB)
#define OFF_CNT   32768                    // int
#define OFF_GDONE 33024                    // 512 i32 (2 KB)
#define OFF_LIST  35072                    // 32768 i32 (128 KB)
#define OFF_FIXB  166144                   // 32768 u64 (256 KB)
#define OFF_EHT   524288                   // 32*8192*8 bf16 = 4 MB
#define OFF_ELT   (OFF_EHT + 4194304)
#define MAXGRP    512
#define WS_NEED   ((size_t)(OFF_ELT + 4194304))

#define SMEM_BYTES 163840                  // 64K zs_h + 64K zs_l + 32K esq

#define GLOAD_LDS16(g, s) \
  __builtin_amdgcn_global_load_lds((const __attribute__((address_space(1))) unsigned int*)(g), \
                                   (__attribute__((address_space(3))) unsigned int*)(s), 16, 0, 0)

static __device__ __forceinline__ short f32_to_bf16(float f) {
  unsigned u = __float_as_uint(f);
  unsigned r = (u + 0x7FFFu + ((u >> 16) & 1u)) >> 16;   // RNE
  return (short)r;
}
static __device__ __forceinline__ float bf16_to_f32(short s) {
  return __uint_as_float(((unsigned)(unsigned short)s) << 16);
}

// ===========================================================================
// P: eht/elt[c][k][8] = bf16 hi/lo split of e[k][8c+j], coalesced stores
// (lanes k-major -> 16B/lane consecutive). esq[k] via LDS reduce. Zeros
// cnt + gdone.
// ===========================================================================
__global__ __launch_bounds__(256) void eprep_kernel(const float* __restrict__ e,
                                                    short* __restrict__ eht,
                                                    short* __restrict__ elt,
                                                    float* __restrict__ esq,
                                                    int* __restrict__ cnt,
                                                    int* __restrict__ gdone) {
  __shared__ float ps[4 * 64];
  const int tid = threadIdx.x;
  const int kk = tid & 63, cc = tid >> 6;     // code-in-group, c-quarter
  const int k = blockIdx.x * 64 + kk;
  if (blockIdx.x == 0) {
    if (tid == 0) *cnt = 0;
    if (tid < 256) { gdone[tid] = 0; gdone[tid + 256] = 0; }
  }
  float ss = 0.f;
  #pragma unroll
  for (int c2 = 0; c2 < 8; ++c2) {
    const int c = cc * 8 + c2;
    f32x4 v0 = *(const f32x4*)(e + (size_t)k * D_DIM + c * 8);
    f32x4 v1 = *(const f32x4*)(e + (size_t)k * D_DIM + c * 8 + 4);
    float v[8] = {v0[0], v0[1], v0[2], v0[3], v1[0], v1[1], v1[2], v1[3]};
    s16x8 hv, lv;
    #pragma unroll
    for (int i = 0; i < 8; ++i) {
      ss += v[i] * v[i];
      short h = f32_to_bf16(v[i]);
      short l = f32_to_bf16(v[i] - bf16_to_f32(h));
      hv[i] = h; lv[i] = l;
    }
    *(s16x8*)(eht + ((size_t)c * K_CB + k) * 8) = hv;   // coalesced over kk
    *(s16x8*)(elt + ((size_t)c * K_CB + k) * 8) = lv;
  }
  ps[cc * 64 + kk] = ss;
  __syncthreads();
  if (tid < 64)
    esq[blockIdx.x * 64 + tid] = ps[tid] + ps[64 + tid] + ps[128 + tid] + ps[192 + tid];
}

// ===========================================================================
// Main: 256 blocks x 512 thr (8 waves, 2/SIMD). 128 tokens/block in LDS.
// R4-R7 all pinned at MfmaUtil~48% regardless of occupancy / VMEM-per-MFMA /
// LDS-per-MFMA => per-iteration e-load latency serialization is the wall.
// This round: explicit 2-deep register ping-pong pipeline -- e-frags for
// dc+1 (and the next chunk's dc=0, latency covered by the epilogue) are in
// flight while the current MFMA block runs. Wave (th=w>>2, cg=w&3), f=4 x
// j=2 frags of mfma_f32_32x32x16_bf16, 3-term bf16-split (hh+hl+lh).
// ===========================================================================
__global__ __launch_bounds__(512, 2) void vq_main_kernel(
    const float* __restrict__ z, const float* __restrict__ e,
    const float* __restrict__ esq_g,
    const short* __restrict__ eht, const short* __restrict__ elt,
    float* __restrict__ out,
    int* __restrict__ cnt, int* __restrict__ list,
    unsigned long long* __restrict__ fixb) {
  extern __shared__ char smem[];
  short* zs_h = (short*)(smem);                 // [32][128][8] = 64 KB
  short* zs_l = (short*)(smem + 65536);         // 64 KB
  float* eqs  = (float*)(smem + 131072);        // [8192] f32 = 32 KB

  const int tid  = threadIdx.x;
  const int w    = tid >> 6;          // wave 0..7
  const int lane = tid & 63;
  const int half = lane >> 5;
  const int l31  = lane & 31;
  const int th   = w >> 2;            // token half (0/1)
  const int cg   = w & 3;             // code subgroup (128 codes each)
  const int n0   = blockIdx.x * 128;

  // ---- stage all esq once: 32 KB, 4 insts/wave ----
  #pragma unroll
  for (int i = 0; i < 4; ++i) {
    int idx = (w * 4 + i) * 256;
    GLOAD_LDS16(esq_g + idx + lane * 4, eqs + idx);
  }

  // ---- split -2*z into bf16 hi/lo directly into LDS (fused zprep) ----
  {
    const int t = tid & 127;
    const int cb = (tid >> 7) * 8;    // 0,8,16,24
    #pragma unroll
    for (int cc = 0; cc < 8; ++cc) {
      const int c = cb + cc;
      s16x8 hv, lv;
      #pragma unroll
      for (int i = 0; i < 8; ++i) {
        float x = -2.0f * z[(size_t)(c * 8 + i) * N_TOK + n0 + t];  // coalesced over t
        short h = f32_to_bf16(x);
        short l = f32_to_bf16(x - bf16_to_f32(h));
        hv[i] = h; lv[i] = l;
      }
      *(s16x8*)(zs_h + ((size_t)c * 128 + t) * 8) = hv;
      *(s16x8*)(zs_l + ((size_t)c * 128 + t) * 8) = lv;
    }
  }
  __syncthreads();   // the only barrier before the merge

  float bestv[2] = {3.4e38f, 3.4e38f};
  float secv[2]  = {3.4e38f, 3.4e38f};
  int   bestk[2] = {0, 0};

#define LOADE(EH, EL, DC, KB) do {                                          \
    const size_t eb_ = ((size_t)(2 * (DC) + half) * K_CB + (KB) + l31) * 8; \
    EH[0] = *(const s16x8*)(eht + eb_);                                     \
    EH[1] = *(const s16x8*)(eht + eb_ + 256);                               \
    EH[2] = *(const s16x8*)(eht + eb_ + 512);                               \
    EH[3] = *(const s16x8*)(eht + eb_ + 768);                               \
    EL[0] = *(const s16x8*)(elt + eb_);                                     \
    EL[1] = *(const s16x8*)(elt + eb_ + 256);                               \
    EL[2] = *(const s16x8*)(elt + eb_ + 512);                               \
    EL[3] = *(const s16x8*)(elt + eb_ + 768);                               \
  } while (0)

#define STEP(EH, EL, DC) do {                                               \
    const int zb_ = ((2 * (DC) + half) * 128 + th * 64 + l31) * 8;          \
    s16x8 bh0 = *(const s16x8*)(zs_h + zb_);                                \
    s16x8 bh1 = *(const s16x8*)(zs_h + zb_ + 256);                          \
    s16x8 bl0 = *(const s16x8*)(zs_l + zb_);                                \
    s16x8 bl1 = *(const s16x8*)(zs_l + zb_ + 256);                          \
    _Pragma("unroll")                                                       \
    for (int f_ = 0; f_ < 4; ++f_) {                                        \
      acc[f_][0] = __builtin_amdgcn_mfma_f32_32x32x16_bf16(EH[f_], bh0, acc[f_][0], 0, 0, 0); \
      acc[f_][1] = __builtin_amdgcn_mfma_f32_32x32x16_bf16(EH[f_], bh1, acc[f_][1], 0, 0, 0); \
      acc[f_][0] = __builtin_amdgcn_mfma_f32_32x32x16_bf16(EH[f_], bl0, acc[f_][0], 0, 0, 0); \
      acc[f_][1] = __builtin_amdgcn_mfma_f32_32x32x16_bf16(EH[f_], bl1, acc[f_][1], 0, 0, 0); \
      acc[f_][0] = __builtin_amdgcn_mfma_f32_32x32x16_bf16(EL[f_], bh0, acc[f_][0], 0, 0, 0); \
      acc[f_][1] = __builtin_amdgcn_mfma_f32_32x32x16_bf16(EL[f_], bh1, acc[f_][1], 0, 0, 0); \
    }                                                                       \
  } while (0)

  s16x8 eAh[4], eAl[4], eBh[4], eBl[4];
  LOADE(eAh, eAl, 0, cg * 128);                 // prologue: first chunk, dc=0

  for (int k0 = 0; k0 < K_CB; k0 += 512) {
    const int kb = k0 + cg * 128;
    f32x16 acc[4][2];
    #pragma unroll
    for (int f = 0; f < 4; ++f)
      #pragma unroll
      for (int j = 0; j < 2; ++j)
        #pragma unroll
        for (int r = 0; r < 16; ++r) acc[f][j][r] = 0.f;

    #pragma unroll
    for (int dc = 0; dc < 16; dc += 2) {
      LOADE(eBh, eBl, dc + 1, kb);              // in flight during STEP A
      STEP(eAh, eAl, dc);
      if (dc + 2 < 16) {
        LOADE(eAh, eAl, dc + 2, kb);            // in flight during STEP B
      } else {
        const int kbn = (k0 + 512 < K_CB ? k0 + 512 : 0) + cg * 128;
        LOADE(eAh, eAl, 0, kbn);                // cross-chunk prefetch (epilogue covers)
      }
      STEP(eBh, eBl, dc + 1);
    }

    // epilogue: score = acc + esq; running best/second (k ascending per lane)
    #pragma unroll
    for (int f = 0; f < 4; ++f) {
      const int base = kb + 32 * f + 4 * half;
      #pragma unroll
      for (int g = 0; g < 4; ++g) {
        f32x4 eqv = *(const f32x4*)(eqs + base + 8 * g);    // broadcast read
        #pragma unroll
        for (int r = 0; r < 4; ++r) {
          const int reg = g * 4 + r;
          const int kglob = base + 8 * g + r;
          #pragma unroll
          for (int j = 0; j < 2; ++j) {
            float s = acc[f][j][reg] + eqv[r];
            if (s < bestv[j]) { secv[j] = bestv[j]; bestv[j] = s; bestk[j] = kglob; }
            else if (s < secv[j]) secv[j] = s;
          }
        }
      }
    }
  }

  // ---- cross-wave merge: 8 partials per token (4 cg x 2 halves; th in t) ----
  __syncthreads();
  float* pv  = (float*)(smem);                  // [8][128]
  int*   pk  = (int*)  (smem + 4096);
  float* ps  = (float*)(smem + 8192);
  int*   fin = (int*)  (smem + 12288);          // [128]
  const int slot = cg * 2 + half;
  #pragma unroll
  for (int j = 0; j < 2; ++j) {
    const int t = th * 64 + 32 * j + l31;
    pv[slot * 128 + t] = bestv[j];
    pk[slot * 128 + t] = bestk[j];
    ps[slot * 128 + t] = secv[j];
  }
  __syncthreads();
  if (tid < 128) {
    const int t = tid;
    float bv = pv[t]; int bk = pk[t]; float sc = ps[t];
    #pragma unroll
    for (int s2 = 1; s2 < 8; ++s2) {
      float v = pv[s2 * 128 + t]; int k2 = pk[s2 * 128 + t]; float s3 = ps[s2 * 128 + t];
      if (v < bv || (v == bv && k2 < bk)) { sc = fminf(bv, s3); bv = v; bk = k2; }
      else                                { sc = fminf(sc, v); }
    }
    fin[t] = bk;
    const int n = n0 + t;
    out[(size_t)D_DIM * N_TOK + n] = (float)bk;     // indices as float (exact)
    if (sc - bv < TAU) {                            // flag for exact rescan
      int p = atomicAdd(cnt, 1);
      list[p] = n;
      fixb[n] = 0xFFFFFFFFFFFFFFFFULL;
    }
  }
  __syncthreads();

  // ---- z_q gather: float4 codebook loads, coalesced stores over t ----
  {
    const int t = tid & 127, d0 = tid >> 7;         // d0 0..3
    const int kk = fin[t];
    const f32x4* row = (const f32x4*)(e + (size_t)kk * D_DIM) + d0 * 16;
    #pragma unroll 4
    for (int q = 0; q < 16; ++q) {
      f32x4 v = row[q];
      const int d = d0 * 64 + q * 4;
      out[(size_t)(d + 0) * N_TOK + n0 + t] = v[0];
      out[(size_t)(d + 1) * N_TOK + n0 + t] = v[1];
      out[(size_t)(d + 2) * N_TOK + n0 + t] = v[2];
      out[(size_t)(d + 3) * N_TOK + n0 + t] = v[3];
    }
  }
#undef LOADE
#undef STEP
}

// ===========================================================================
// C2: fused gather + exact fp32 rescan + finisher. Persistent grid over
// items = (64-token group) x (128-code slab); 64 items per group. Each item
// stages its group's z columns directly (scattered, L3-served), computes the
// register-tiled fp32 slab, atomicMin-merges packed (f32bits<<32|k). The
// 64th-finishing item of a group writes exact idx + z_q for its 64 tokens.
// ===========================================================================
__global__ __launch_bounds__(256) void rescan_kernel(
    const float* __restrict__ z, const float* __restrict__ e,
    const float* __restrict__ esq, const int* __restrict__ cnt,
    const int* __restrict__ list, unsigned long long* __restrict__ fixb,
    int* __restrict__ gdone, float* __restrict__ out) {
  __shared__ float zs[D_DIM * 64];                 // 64 KB, zs[d*64 + t]
  __shared__ unsigned long long red[16 * 64];      // 8 KB
  __shared__ int fk[64], fn[64], lastflag;
  const int tid = threadIdx.x;
  const int c = *(volatile const int*)cnt;
  if (c == 0) return;
  int groups = (c + 63) >> 6;
  if (groups > MAXGRP) groups = MAXGRP;
  const int items = groups * 64;                   // 64 slabs of 128 codes
  const int tx = tid & 15, ty = tid >> 4;

  for (int it = blockIdx.x; it < items; it += gridDim.x) {
    const int g = it >> 6;
    const int slab = (it & 63) * 128;
    __syncthreads();                               // protect zs/red reuse
    // ---- stage z columns for this group (fused gather) ----
    {
      const int t = tid & 63, dq = tid >> 6;       // dq 0..3
      const int idx = g * 64 + t;
      const int n = list[idx < c ? idx : c - 1];
      #pragma unroll 4
      for (int dd = 0; dd < 64; ++dd) {
        const int d = dq * 64 + dd;
        zs[d * 64 + t] = z[(size_t)d * N_TOK + n];
      }
    }
    __syncthreads();

    unsigned long long lmin[4] = {~0ULL, ~0ULL, ~0ULL, ~0ULL};
    #pragma unroll
    for (int k0 = 0; k0 < 128; k0 += 64) {
      const f32x4* er[4]; float eqv[4];
      #pragma unroll
      for (int j = 0; j < 4; ++j) {
        int k = slab + k0 + ty + 16 * j;
        er[j] = (const f32x4*)(e + (size_t)k * D_DIM);
        eqv[j] = esq[k];
      }
      float acc[4][4];
      #pragma unroll
      for (int i = 0; i < 4; ++i)
        #pragma unroll
        for (int j = 0; j < 4; ++j) acc[i][j] = 0.f;
      #pragma unroll 4
      for (int d4 = 0; d4 < D_DIM / 4; ++d4) {
        f32x4 ev[4];
        #pragma unroll
        for (int j = 0; j < 4; ++j) ev[j] = er[j][d4];
        #pragma unroll
        for (int dd = 0; dd < 4; ++dd) {
          float zv[4];
          #pragma unroll
          for (int i = 0; i < 4; ++i) zv[i] = zs[(d4 * 4 + dd) * 64 + tx + 16 * i];
          #pragma unroll
          for (int i = 0; i < 4; ++i)
            #pragma unroll
            for (int j = 0; j < 4; ++j) acc[i][j] += zv[i] * ev[j][dd];
        }
      }
      #pragma unroll
      for (int j = 0; j < 4; ++j) {
        const int k = slab + k0 + ty + 16 * j;
        #pragma unroll
        for (int i = 0; i < 4; ++i) {
          float s = eqv[j] - 2.0f * acc[i][j] + 1024.0f;   // bias > 0 for packing
          unsigned long long p =
              ((unsigned long long)__float_as_uint(s) << 32) | (unsigned)k;
          lmin[i] = (p < lmin[i]) ? p : lmin[i];
        }
      }
    }
    #pragma unroll
    for (int i = 0; i < 4; ++i) red[ty * 64 + tx + 16 * i] = lmin[i];
    __syncthreads();
    if (tid < 64) {
      unsigned long long m = red[tid];
      #pragma unroll
      for (int t = 1; t < 16; ++t) {
        unsigned long long v = red[t * 64 + tid];
        m = (v < m) ? v : m;
      }
      const int idx = g * 64 + tid;
      const int n = list[idx < c ? idx : c - 1];
      atomicMin(&fixb[n], m);
    }
    // ---- completion: last item of this group writes outputs ----
    __threadfence();
    __syncthreads();
    if (tid == 0) lastflag = (atomicAdd(&gdone[g], 1) == 63) ? 1 : 0;
    __syncthreads();
    if (lastflag) {
      if (tid < 64) {
        const int idx = g * 64 + tid;
        int kres = -1, n = -1;
        if (idx < c) {
          n = list[idx];
          unsigned long long mv = atomicMin(&fixb[n], 0xFFFFFFFFFFFFFFFFULL);
          kres = (int)(unsigned)(mv & 0xFFFFFFFFu);
          out[(size_t)D_DIM * N_TOK + n] = (float)kres;
        }
        fk[tid] = kres; fn[tid] = n;
      }
      __syncthreads();
      {
        const int t = tid & 63, dq = tid >> 6;
        const int kres = fk[t];
        if (kres >= 0) {
          const int n = fn[t];
          const float* row = e + (size_t)kres * D_DIM;
          #pragma unroll 4
          for (int dd = 0; dd < 64; ++dd) {
            const int d = dq * 64 + dd;
            out[(size_t)d * N_TOK + n] = row[d];
          }
        }
      }
    }
  }
}

// ======================= fallback (round-1 fp32 path) =======================
__global__ __launch_bounds__(256) void esq_kernel(const float* __restrict__ e,
                                                  float* __restrict__ esq) {
  const int wave = threadIdx.x >> 6, lane = threadIdx.x & 63;
  const int k = blockIdx.x * 4 + wave;
  const float4* row = (const float4*)(e + (size_t)k * D_DIM);
  float4 v = row[lane];
  float s = v.x*v.x + v.y*v.y + v.z*v.z + v.w*v.w;
  #pragma unroll
  for (int off = 32; off > 0; off >>= 1) s += __shfl_down(s, off, 64);
  if (lane == 0) esq[k] = s;
}

__global__ __launch_bounds__(256) void vq_kernel(const float* __restrict__ z,
                                                 const float* __restrict__ e,
                                                 const float* __restrict__ esq,
                                                 float* __restrict__ out) {
  __shared__ float zs[D_DIM][64];
  const int tid = threadIdx.x, tx = tid & 15, ty = tid >> 4;
  const int n0 = blockIdx.x * 64;
  {
    const int c = tid & 63, d0 = tid >> 6;
    #pragma unroll 4
    for (int d = d0; d < D_DIM; d += 4) zs[d][c] = z[(size_t)d * N_TOK + n0 + c];
  }
  __syncthreads();
  float bestv[4] = {3.4e38f,3.4e38f,3.4e38f,3.4e38f};
  int   besti[4] = {0,0,0,0};
  for (int k0 = 0; k0 < K_CB; k0 += 64) {
    const float4* er[4]; float eqv[4];
    #pragma unroll
    for (int j = 0; j < 4; ++j) {
      int k = k0 + ty + 16 * j;
      er[j] = (const float4*)(e + (size_t)k * D_DIM);
      eqv[j] = esq[k];
    }
    float acc[4][4];
    #pragma unroll
    for (int i = 0; i < 4; ++i)
      #pragma unroll
      for (int j = 0; j < 4; ++j) acc[i][j] = 0.f;
    #pragma unroll 4
    for (int d4 = 0; d4 < D_DIM/4; ++d4) {
      float4 ev[4];
      #pragma unroll
      for (int j = 0; j < 4; ++j) ev[j] = er[j][d4];
      #pragma unroll
      for (int dd = 0; dd < 4; ++dd) {
        float zv[4];
        #pragma unroll
        for (int i = 0; i < 4; ++i) zv[i] = zs[d4*4+dd][tx + 16*i];
        #pragma unroll
        for (int i = 0; i < 4; ++i)
          #pragma unroll
          for (int j = 0; j < 4; ++j) acc[i][j] += zv[i] * ((const float*)&ev[j])[dd];
      }
    }
    #pragma unroll
    for (int j = 0; j < 4; ++j) {
      int k = k0 + ty + 16 * j;
      #pragma unroll
      for (int i = 0; i < 4; ++i) {
        float s = eqv[j] - 2.0f * acc[i][j];
        if (s < bestv[i]) { bestv[i] = s; besti[i] = k; }
      }
    }
  }
  __syncthreads();
  float* lds = &zs[0][0];
  float* vred = lds; int* ired = (int*)lds + 1024; int* fin = (int*)lds + 2048;
  #pragma unroll
  for (int i = 0; i < 4; ++i) {
    int l = tx + 16 * i;
    vred[ty * 64 + l] = bestv[i]; ired[ty * 64 + l] = besti[i];
  }
  __syncthreads();
  if (tid < 64) {
    float bv = vred[tid]; int bi = ired[tid];
    #pragma unroll
    for (int t = 1; t < 16; ++t) {
      float v = vred[t*64+tid]; int ix = ired[t*64+tid];
      if (v < bv || (v == bv && ix < bi)) { bv = v; bi = ix; }
    }
    fin[tid] = bi;
    out[(size_t)D_DIM * N_TOK + n0 + tid] = (float)bi;
  }
  __syncthreads();
  {
    const int l = tid & 63, d0 = tid >> 6;
    const int kk = fin[l];
    const float* row = e + (size_t)kk * D_DIM;
    #pragma unroll 4
    for (int d = d0; d < D_DIM; d += 4) out[(size_t)d * N_TOK + n0 + l] = row[d];
  }
}

extern "C" void kernel_launch(void* const* d_in, const int* in_sizes, int n_in,
                              void* d_out, int out_size, void* d_ws, size_t ws_size,
                              hipStream_t stream) {
  const float* z = (const float*)d_in[0];
  const float* e = (const float*)d_in[1];
  float* out = (float*)d_out;
  char* ws = (char*)d_ws;

  if (ws_size >= WS_NEED) {
    float* esq = (float*)(ws + OFF_ESQ);
    int* cnt = (int*)(ws + OFF_CNT);
    int* gdone = (int*)(ws + OFF_GDONE);
    int* list = (int*)(ws + OFF_LIST);
    unsigned long long* fixb = (unsigned long long*)(ws + OFF_FIXB);
    short* eht = (short*)(ws + OFF_EHT);
    short* elt = (short*)(ws + OFF_ELT);

    (void)hipFuncSetAttribute((const void*)vq_main_kernel,
                              hipFuncAttributeMaxDynamicSharedMemorySize, SMEM_BYTES);

    eprep_kernel<<<128, 256, 0, stream>>>(e, eht, elt, esq, cnt, gdone);
    vq_main_kernel<<<256, 512, SMEM_BYTES, stream>>>(z, e, esq, eht, elt,
                                                     out, cnt, list, fixb);
    rescan_kernel<<<512, 256, 0, stream>>>(z, e, esq, cnt, list, fixb, gdone, out);
  } else {
    float* esq = (float*)(ws);
    esq_kernel<<<K_CB / 4, 256, 0, stream>>>(e, esq);
    vq_kernel<<<N_TOK / 64, 256, 0, stream>>>(z, e, esq, out);
  }
}

// Round 9
// 533.776 us; speedup vs baseline: 1.3672x; 1.3672x over previous
//
#include <hip/hip_runtime.h>

#define D_DIM 256
#define N_TOK 32768
#define K_CB  8192
#define TAU   0.03f

typedef float  f32x16 __attribute__((ext_vector_type(16)));
typedef float  f32x4  __attribute__((ext_vector_type(4)));
typedef short  s16x8  __attribute__((ext_vector_type(8)));

// ---- workspace layout (bytes) ----
#define OFF_ESQ   0                        // 8192 f32 (32 KB)
#define OFF_CNT   32768                    // int
#define OFF_GDONE 33024                    // 512 i32 (2 KB)
#define OFF_LIST  35072                    // 32768 i32 (128 KB)
#define OFF_FIXB  166144                   // 32768 u64 (256 KB)
#define OFF_EHT   524288                   // 32*8192*8 bf16 = 4 MB
#define OFF_ELT   (OFF_EHT + 4194304)
#define MAXGRP    512
#define WS_NEED   ((size_t)(OFF_ELT + 4194304))

#define SMEM_BYTES 163840                  // 64K zs_h + 64K zs_l + 32K esq

#define GLOAD_LDS16(g, s) \
  __builtin_amdgcn_global_load_lds((const __attribute__((address_space(1))) unsigned int*)(g), \
                                   (__attribute__((address_space(3))) unsigned int*)(s), 16, 0, 0)

static __device__ __forceinline__ short f32_to_bf16(float f) {
  unsigned u = __float_as_uint(f);
  unsigned r = (u + 0x7FFFu + ((u >> 16) & 1u)) >> 16;   // RNE
  return (short)r;
}
static __device__ __forceinline__ float bf16_to_f32(short s) {
  return __uint_as_float(((unsigned)(unsigned short)s) << 16);
}

// ===========================================================================
// P: eht/elt[c][k][8] = bf16 hi/lo split of e[k][8c+j], coalesced stores
// (lanes k-major -> 16B/lane consecutive). esq[k] via LDS reduce. Zeros
// cnt + gdone.
// ===========================================================================
__global__ __launch_bounds__(256) void eprep_kernel(const float* __restrict__ e,
                                                    short* __restrict__ eht,
                                                    short* __restrict__ elt,
                                                    float* __restrict__ esq,
                                                    int* __restrict__ cnt,
                                                    int* __restrict__ gdone) {
  __shared__ float ps[4 * 64];
  const int tid = threadIdx.x;
  const int kk = tid & 63, cc = tid >> 6;     // code-in-group, c-quarter
  const int k = blockIdx.x * 64 + kk;
  if (blockIdx.x == 0) {
    if (tid == 0) *cnt = 0;
    if (tid < 256) { gdone[tid] = 0; gdone[tid + 256] = 0; }
  }
  float ss = 0.f;
  #pragma unroll
  for (int c2 = 0; c2 < 8; ++c2) {
    const int c = cc * 8 + c2;
    f32x4 v0 = *(const f32x4*)(e + (size_t)k * D_DIM + c * 8);
    f32x4 v1 = *(const f32x4*)(e + (size_t)k * D_DIM + c * 8 + 4);
    float v[8] = {v0[0], v0[1], v0[2], v0[3], v1[0], v1[1], v1[2], v1[3]};
    s16x8 hv, lv;
    #pragma unroll
    for (int i = 0; i < 8; ++i) {
      ss += v[i] * v[i];
      short h = f32_to_bf16(v[i]);
      short l = f32_to_bf16(v[i] - bf16_to_f32(h));
      hv[i] = h; lv[i] = l;
    }
    *(s16x8*)(eht + ((size_t)c * K_CB + k) * 8) = hv;   // coalesced over kk
    *(s16x8*)(elt + ((size_t)c * K_CB + k) * 8) = lv;
  }
  ps[cc * 64 + kk] = ss;
  __syncthreads();
  if (tid < 64)
    esq[blockIdx.x * 64 + tid] = ps[tid] + ps[64 + tid] + ps[128 + tid] + ps[192 + tid];
}

// ===========================================================================
// Main: 256 blocks x 512 thr (8 waves, 2/SIMD) -- the R7 K-loop (proven
// 403 us, VGPR 96, zero spill; R8's explicit ping-pong spilled to scratch
// and regressed). 128 tokens/block in LDS (hi/lo bf16, split in-register).
// e streams GLOBAL->VGPR. Wave (th=w>>2, cg=w&3): 128 codes x 64 tokens via
// f=4 x j=2 frags of mfma_f32_32x32x16_bf16, 3-term bf16-split (hh+hl+lh).
// score = esq[k] + dot(-2z, e). Tracks best+second; margin<TAU -> rescan.
// ===========================================================================
__global__ __launch_bounds__(512, 2) void vq_main_kernel(
    const float* __restrict__ z, const float* __restrict__ e,
    const float* __restrict__ esq_g,
    const short* __restrict__ eht, const short* __restrict__ elt,
    float* __restrict__ out,
    int* __restrict__ cnt, int* __restrict__ list,
    unsigned long long* __restrict__ fixb) {
  extern __shared__ char smem[];
  short* zs_h = (short*)(smem);                 // [32][128][8] = 64 KB
  short* zs_l = (short*)(smem + 65536);         // 64 KB
  float* eqs  = (float*)(smem + 131072);        // [8192] f32 = 32 KB

  const int tid  = threadIdx.x;
  const int w    = tid >> 6;          // wave 0..7
  const int lane = tid & 63;
  const int half = lane >> 5;
  const int l31  = lane & 31;
  const int th   = w >> 2;            // token half (0/1)
  const int cg   = w & 3;             // code subgroup (128 codes each)
  const int n0   = blockIdx.x * 128;

  // ---- stage all esq once: 32 KB, 4 insts/wave ----
  #pragma unroll
  for (int i = 0; i < 4; ++i) {
    int idx = (w * 4 + i) * 256;
    GLOAD_LDS16(esq_g + idx + lane * 4, eqs + idx);
  }

  // ---- split -2*z into bf16 hi/lo directly into LDS (fused zprep) ----
  {
    const int t = tid & 127;
    const int cb = (tid >> 7) * 8;    // 0,8,16,24
    #pragma unroll
    for (int cc = 0; cc < 8; ++cc) {
      const int c = cb + cc;
      s16x8 hv, lv;
      #pragma unroll
      for (int i = 0; i < 8; ++i) {
        float x = -2.0f * z[(size_t)(c * 8 + i) * N_TOK + n0 + t];  // coalesced over t
        short h = f32_to_bf16(x);
        short l = f32_to_bf16(x - bf16_to_f32(h));
        hv[i] = h; lv[i] = l;
      }
      *(s16x8*)(zs_h + ((size_t)c * 128 + t) * 8) = hv;
      *(s16x8*)(zs_l + ((size_t)c * 128 + t) * 8) = lv;
    }
  }
  __syncthreads();   // the only barrier before the merge

  float bestv[2] = {3.4e38f, 3.4e38f};
  float secv[2]  = {3.4e38f, 3.4e38f};
  int   bestk[2] = {0, 0};

  for (int k0 = 0; k0 < K_CB; k0 += 512) {
    const int kb = k0 + cg * 128;
    f32x16 acc[4][2];
    #pragma unroll
    for (int f = 0; f < 4; ++f)
      #pragma unroll
      for (int j = 0; j < 2; ++j)
        #pragma unroll
        for (int r = 0; r < 16; ++r) acc[f][j][r] = 0.f;

    #pragma unroll 2
    for (int dc = 0; dc < 16; ++dc) {
      s16x8 ah[4], al[4], bh[2], bl[2];
      const size_t ebase = ((size_t)(2 * dc + half) * K_CB + kb + l31) * 8;
      #pragma unroll
      for (int f = 0; f < 4; ++f) {
        ah[f] = *(const s16x8*)(eht + ebase + f * 32 * 8);   // global, coalesced 16B/lane
        al[f] = *(const s16x8*)(elt + ebase + f * 32 * 8);
      }
      const int zbase = ((2 * dc + half) * 128 + th * 64 + l31) * 8;
      #pragma unroll
      for (int j = 0; j < 2; ++j) {
        bh[j] = *(const s16x8*)(zs_h + zbase + j * 32 * 8);
        bl[j] = *(const s16x8*)(zs_l + zbase + j * 32 * 8);
      }
      #pragma unroll
      for (int f = 0; f < 4; ++f)
        #pragma unroll
        for (int j = 0; j < 2; ++j) {
          acc[f][j] = __builtin_amdgcn_mfma_f32_32x32x16_bf16(ah[f], bh[j], acc[f][j], 0, 0, 0);
          acc[f][j] = __builtin_amdgcn_mfma_f32_32x32x16_bf16(ah[f], bl[j], acc[f][j], 0, 0, 0);
          acc[f][j] = __builtin_amdgcn_mfma_f32_32x32x16_bf16(al[f], bh[j], acc[f][j], 0, 0, 0);
        }
    }

    // epilogue: score = acc + esq; running best/second (k ascending per lane)
    #pragma unroll
    for (int f = 0; f < 4; ++f) {
      const int base = kb + 32 * f + 4 * half;
      #pragma unroll
      for (int g = 0; g < 4; ++g) {
        f32x4 eqv = *(const f32x4*)(eqs + base + 8 * g);    // broadcast read
        #pragma unroll
        for (int r = 0; r < 4; ++r) {
          const int reg = g * 4 + r;
          const int kglob = base + 8 * g + r;
          #pragma unroll
          for (int j = 0; j < 2; ++j) {
            float s = acc[f][j][reg] + eqv[r];
            if (s < bestv[j]) { secv[j] = bestv[j]; bestv[j] = s; bestk[j] = kglob; }
            else if (s < secv[j]) secv[j] = s;
          }
        }
      }
    }
  }

  // ---- cross-wave merge: 8 partials per token (4 cg x 2 halves; th in t) ----
  __syncthreads();
  float* pv  = (float*)(smem);                  // [8][128]
  int*   pk  = (int*)  (smem + 4096);
  float* ps  = (float*)(smem + 8192);
  int*   fin = (int*)  (smem + 12288);          // [128]
  const int slot = cg * 2 + half;
  #pragma unroll
  for (int j = 0; j < 2; ++j) {
    const int t = th * 64 + 32 * j + l31;
    pv[slot * 128 + t] = bestv[j];
    pk[slot * 128 + t] = bestk[j];
    ps[slot * 128 + t] = secv[j];
  }
  __syncthreads();
  if (tid < 128) {
    const int t = tid;
    float bv = pv[t]; int bk = pk[t]; float sc = ps[t];
    #pragma unroll
    for (int s2 = 1; s2 < 8; ++s2) {
      float v = pv[s2 * 128 + t]; int k2 = pk[s2 * 128 + t]; float s3 = ps[s2 * 128 + t];
      if (v < bv || (v == bv && k2 < bk)) { sc = fminf(bv, s3); bv = v; bk = k2; }
      else                                { sc = fminf(sc, v); }
    }
    fin[t] = bk;
    const int n = n0 + t;
    out[(size_t)D_DIM * N_TOK + n] = (float)bk;     // indices as float (exact)
    if (sc - bv < TAU) {                            // flag for exact rescan
      int p = atomicAdd(cnt, 1);
      list[p] = n;
      fixb[n] = 0xFFFFFFFFFFFFFFFFULL;
    }
  }
  __syncthreads();

  // ---- z_q gather: float4 codebook loads, coalesced stores over t ----
  {
    const int t = tid & 127, d0 = tid >> 7;         // d0 0..3
    const int kk = fin[t];
    const f32x4* row = (const f32x4*)(e + (size_t)kk * D_DIM) + d0 * 16;
    #pragma unroll 4
    for (int q = 0; q < 16; ++q) {
      f32x4 v = row[q];
      const int d = d0 * 64 + q * 4;
      out[(size_t)(d + 0) * N_TOK + n0 + t] = v[0];
      out[(size_t)(d + 1) * N_TOK + n0 + t] = v[1];
      out[(size_t)(d + 2) * N_TOK + n0 + t] = v[2];
      out[(size_t)(d + 3) * N_TOK + n0 + t] = v[3];
    }
  }
}

// ===========================================================================
// C2: fused gather + exact fp32 rescan + finisher. Persistent grid over
// items = (64-token group) x (128-code slab); 64 items per group. Each item
// stages its group's z columns directly (scattered, L3-served), computes the
// register-tiled fp32 slab, atomicMin-merges packed (f32bits<<32|k). The
// 64th-finishing item of a group writes exact idx + z_q for its 64 tokens.
// ===========================================================================
__global__ __launch_bounds__(256) void rescan_kernel(
    const float* __restrict__ z, const float* __restrict__ e,
    const float* __restrict__ esq, const int* __restrict__ cnt,
    const int* __restrict__ list, unsigned long long* __restrict__ fixb,
    int* __restrict__ gdone, float* __restrict__ out) {
  __shared__ float zs[D_DIM * 64];                 // 64 KB, zs[d*64 + t]
  __shared__ unsigned long long red[16 * 64];      // 8 KB
  __shared__ int fk[64], fn[64], lastflag;
  const int tid = threadIdx.x;
  const int c = *(volatile const int*)cnt;
  if (c == 0) return;
  int groups = (c + 63) >> 6;
  if (groups > MAXGRP) groups = MAXGRP;
  const int items = groups * 64;                   // 64 slabs of 128 codes
  const int tx = tid & 15, ty = tid >> 4;

  for (int it = blockIdx.x; it < items; it += gridDim.x) {
    const int g = it >> 6;
    const int slab = (it & 63) * 128;
    __syncthreads();                               // protect zs/red reuse
    // ---- stage z columns for this group (fused gather) ----
    {
      const int t = tid & 63, dq = tid >> 6;       // dq 0..3
      const int idx = g * 64 + t;
      const int n = list[idx < c ? idx : c - 1];
      #pragma unroll 4
      for (int dd = 0; dd < 64; ++dd) {
        const int d = dq * 64 + dd;
        zs[d * 64 + t] = z[(size_t)d * N_TOK + n];
      }
    }
    __syncthreads();

    unsigned long long lmin[4] = {~0ULL, ~0ULL, ~0ULL, ~0ULL};
    #pragma unroll
    for (int k0 = 0; k0 < 128; k0 += 64) {
      const f32x4* er[4]; float eqv[4];
      #pragma unroll
      for (int j = 0; j < 4; ++j) {
        int k = slab + k0 + ty + 16 * j;
        er[j] = (const f32x4*)(e + (size_t)k * D_DIM);
        eqv[j] = esq[k];
      }
      float acc[4][4];
      #pragma unroll
      for (int i = 0; i < 4; ++i)
        #pragma unroll
        for (int j = 0; j < 4; ++j) acc[i][j] = 0.f;
      #pragma unroll 4
      for (int d4 = 0; d4 < D_DIM / 4; ++d4) {
        f32x4 ev[4];
        #pragma unroll
        for (int j = 0; j < 4; ++j) ev[j] = er[j][d4];
        #pragma unroll
        for (int dd = 0; dd < 4; ++dd) {
          float zv[4];
          #pragma unroll
          for (int i = 0; i < 4; ++i) zv[i] = zs[(d4 * 4 + dd) * 64 + tx + 16 * i];
          #pragma unroll
          for (int i = 0; i < 4; ++i)
            #pragma unroll
            for (int j = 0; j < 4; ++j) acc[i][j] += zv[i] * ev[j][dd];
        }
      }
      #pragma unroll
      for (int j = 0; j < 4; ++j) {
        const int k = slab + k0 + ty + 16 * j;
        #pragma unroll
        for (int i = 0; i < 4; ++i) {
          float s = eqv[j] - 2.0f * acc[i][j] + 1024.0f;   // bias > 0 for packing
          unsigned long long p =
              ((unsigned long long)__float_as_uint(s) << 32) | (unsigned)k;
          lmin[i] = (p < lmin[i]) ? p : lmin[i];
        }
      }
    }
    #pragma unroll
    for (int i = 0; i < 4; ++i) red[ty * 64 + tx + 16 * i] = lmin[i];
    __syncthreads();
    if (tid < 64) {
      unsigned long long m = red[tid];
      #pragma unroll
      for (int t = 1; t < 16; ++t) {
        unsigned long long v = red[t * 64 + tid];
        m = (v < m) ? v : m;
      }
      const int idx = g * 64 + tid;
      const int n = list[idx < c ? idx : c - 1];
      atomicMin(&fixb[n], m);
    }
    // ---- completion: last item of this group writes outputs ----
    __threadfence();
    __syncthreads();
    if (tid == 0) lastflag = (atomicAdd(&gdone[g], 1) == 63) ? 1 : 0;
    __syncthreads();
    if (lastflag) {
      if (tid < 64) {
        const int idx = g * 64 + tid;
        int kres = -1, n = -1;
        if (idx < c) {
          n = list[idx];
          unsigned long long mv = atomicMin(&fixb[n], 0xFFFFFFFFFFFFFFFFULL);
          kres = (int)(unsigned)(mv & 0xFFFFFFFFu);
          out[(size_t)D_DIM * N_TOK + n] = (float)kres;
        }
        fk[tid] = kres; fn[tid] = n;
      }
      __syncthreads();
      {
        const int t = tid & 63, dq = tid >> 6;
        const int kres = fk[t];
        if (kres >= 0) {
          const int n = fn[t];
          const float* row = e + (size_t)kres * D_DIM;
          #pragma unroll 4
          for (int dd = 0; dd < 64; ++dd) {
            const int d = dq * 64 + dd;
            out[(size_t)d * N_TOK + n] = row[d];
          }
        }
      }
    }
  }
}

// ======================= fallback (round-1 fp32 path) =======================
__global__ __launch_bounds__(256) void esq_kernel(const float* __restrict__ e,
                                                  float* __restrict__ esq) {
  const int wave = threadIdx.x >> 6, lane = threadIdx.x & 63;
  const int k = blockIdx.x * 4 + wave;
  const float4* row = (const float4*)(e + (size_t)k * D_DIM);
  float4 v = row[lane];
  float s = v.x*v.x + v.y*v.y + v.z*v.z + v.w*v.w;
  #pragma unroll
  for (int off = 32; off > 0; off >>= 1) s += __shfl_down(s, off, 64);
  if (lane == 0) esq[k] = s;
}

__global__ __launch_bounds__(256) void vq_kernel(const float* __restrict__ z,
                                                 const float* __restrict__ e,
                                                 const float* __restrict__ esq,
                                                 float* __restrict__ out) {
  __shared__ float zs[D_DIM][64];
  const int tid = threadIdx.x, tx = tid & 15, ty = tid >> 4;
  const int n0 = blockIdx.x * 64;
  {
    const int c = tid & 63, d0 = tid >> 6;
    #pragma unroll 4
    for (int d = d0; d < D_DIM; d += 4) zs[d][c] = z[(size_t)d * N_TOK + n0 + c];
  }
  __syncthreads();
  float bestv[4] = {3.4e38f,3.4e38f,3.4e38f,3.4e38f};
  int   besti[4] = {0,0,0,0};
  for (int k0 = 0; k0 < K_CB; k0 += 64) {
    const float4* er[4]; float eqv[4];
    #pragma unroll
    for (int j = 0; j < 4; ++j) {
      int k = k0 + ty + 16 * j;
      er[j] = (const float4*)(e + (size_t)k * D_DIM);
      eqv[j] = esq[k];
    }
    float acc[4][4];
    #pragma unroll
    for (int i = 0; i < 4; ++i)
      #pragma unroll
      for (int j = 0; j < 4; ++j) acc[i][j] = 0.f;
    #pragma unroll 4
    for (int d4 = 0; d4 < D_DIM/4; ++d4) {
      float4 ev[4];
      #pragma unroll
      for (int j = 0; j < 4; ++j) ev[j] = er[j][d4];
      #pragma unroll
      for (int dd = 0; dd < 4; ++dd) {
        float zv[4];
        #pragma unroll
        for (int i = 0; i < 4; ++i) zv[i] = zs[d4*4+dd][tx + 16*i];
        #pragma unroll
        for (int i = 0; i < 4; ++i)
          #pragma unroll
          for (int j = 0; j < 4; ++j) acc[i][j] += zv[i] * ((const float*)&ev[j])[dd];
      }
    }
    #pragma unroll
    for (int j = 0; j < 4; ++j) {
      int k = k0 + ty + 16 * j;
      #pragma unroll
      for (int i = 0; i < 4; ++i) {
        float s = eqv[j] - 2.0f * acc[i][j];
        if (s < bestv[i]) { bestv[i] = s; besti[i] = k; }
      }
    }
  }
  __syncthreads();
  float* lds = &zs[0][0];
  float* vred = lds; int* ired = (int*)lds + 1024; int* fin = (int*)lds + 2048;
  #pragma unroll
  for (int i = 0; i < 4; ++i) {
    int l = tx + 16 * i;
    vred[ty * 64 + l] = bestv[i]; ired[ty * 64 + l] = besti[i];
  }
  __syncthreads();
  if (tid < 64) {
    float bv = vred[tid]; int bi = ired[tid];
    #pragma unroll
    for (int t = 1; t < 16; ++t) {
      float v = vred[t*64+tid]; int ix = ired[t*64+tid];
      if (v < bv || (v == bv && ix < bi)) { bv = v; bi = ix; }
    }
    fin[tid] = bi;
    out[(size_t)D_DIM * N_TOK + n0 + tid] = (float)bi;
  }
  __syncthreads();
  {
    const int l = tid & 63, d0 = tid >> 6;
    const int kk = fin[l];
    const float* row = e + (size_t)kk * D_DIM;
    #pragma unroll 4
    for (int d = d0; d < D_DIM; d += 4) out[(size_t)d * N_TOK + n0 + l] = row[d];
  }
}

extern "C" void kernel_launch(void* const* d_in, const int* in_sizes, int n_in,
                              void* d_out, int out_size, void* d_ws, size_t ws_size,
                              hipStream_t stream) {
  const float* z = (const float*)d_in[0];
  const float* e = (const float*)d_in[1];
  float* out = (float*)d_out;
  char* ws = (char*)d_ws;

  if (ws_size >= WS_NEED) {
    float* esq = (float*)(ws + OFF_ESQ);
    int* cnt = (int*)(ws + OFF_CNT);
    int* gdone = (int*)(ws + OFF_GDONE);
    int* list = (int*)(ws + OFF_LIST);
    unsigned long long* fixb = (unsigned long long*)(ws + OFF_FIXB);
    short* eht = (short*)(ws + OFF_EHT);
    short* elt = (short*)(ws + OFF_ELT);

    (void)hipFuncSetAttribute((const void*)vq_main_kernel,
                              hipFuncAttributeMaxDynamicSharedMemorySize, SMEM_BYTES);

    eprep_kernel<<<128, 256, 0, stream>>>(e, eht, elt, esq, cnt, gdone);
    vq_main_kernel<<<256, 512, SMEM_BYTES, stream>>>(z, e, esq, eht, elt,
                                                     out, cnt, list, fixb);
    rescan_kernel<<<512, 256, 0, stream>>>(z, e, esq, cnt, list, fixb, gdone, out);
  } else {
    float* esq = (float*)(ws);
    esq_kernel<<<K_CB / 4, 256, 0, stream>>>(e, esq);
    vq_kernel<<<N_TOK / 64, 256, 0, stream>>>(z, e, esq, out);
  }
}